// Round 7
// baseline (319.760 us; speedup 1.0000x reference)
//
#include <hip/hip_runtime.h>
#include <hip/hip_bf16.h>
#include <math.h>

// Problem constants
#define BATCH 1024
#define NREAL 784
#define NPAD  896      // 7*128 zero-padded graph dim
#define C1D   32
#define C2D   32
#define HDIM  512
#define NCLS  10
#define KFC   25088    // 784*32

#define KS_G1 7        // split-K G1: K=896 -> 128/slice, 4 iters (EVEN)
#define KS_FC 14       // split-K fc1: K=25088 -> 1792/slice, 56 iters (EVEN)

#define BK 32

using bf16x8  = __attribute__((ext_vector_type(8))) __bf16;
using floatx4 = __attribute__((ext_vector_type(4))) float;

__device__ __forceinline__ float elu_f(float t) {
    return t > 0.f ? t : (__expf(t) - 1.f);
}

__device__ __forceinline__ bf16x8 ld8(const __hip_bfloat16* p) {
    return *(const bf16x8*)p;
}

// LDS-only barrier: waits ds ops but leaves global loads (vmcnt) in flight.
__device__ __forceinline__ void wg_barrier_lds() {
    asm volatile("s_waitcnt lgkmcnt(0)\n\ts_barrier" ::: "memory");
}

// ---------------------------------------------------------------------------
// Fragment-major storage (A operands): matrix M[R][K] stored as 1 KB chunks:
// chunk = (row>>4)*(K/32) + (k>>5); elem (row,k) at ((k>>3)&3)*128 +
// (row&15)*8 + (k&7). Lane L's 16 B at L*16 is exactly its 16x16x32 MFMA
// A-fragment (m=L&15, k=(L>>4)*8+j).
// ---------------------------------------------------------------------------

// ---------------------------------------------------------------------------
// HYBRID BT-GEMM: C[row][col] = sum_k A[row][k]*B[col][k].
//   A: fragment-direct from frag-layout global, 2-deep named prefetch —
//      never interacts with barriers (vmcnt stays in flight).
//   B: row-major k-contig global -> named VGPRs -> swizzled LDS dbuf
//      (r5 conflict-free layout) -> ds_read_b128 frags. lgkm-only barriers.
// 128x128 tile, 4 waves (2x2 of 64x64). kIters MUST be even (>=2).
// MODE 1: elu(acc+bias[col&31]) -> bf16 h2f FRAG store, masked n<784  (G3)
// MODE 2: fp32 partial store outF[z*ss + row*ldc + col]            (G1, G4)
// ---------------------------------------------------------------------------
template<int MODE>
__launch_bounds__(256)
__global__ void gemm_hy(const __hip_bfloat16* __restrict__ Af, int kcA,
                        const __hip_bfloat16* __restrict__ Brow, int ldb,
                        int kIters, int kPerZ, size_t sliceStride,
                        float* __restrict__ outF, int ldc,
                        __hip_bfloat16* __restrict__ outH,
                        const float* __restrict__ bias)
{
    __shared__ __align__(16) __hip_bfloat16 Bs[2][128 * BK];   // 8 KB each

    const int tid  = threadIdx.x;
    const int lane = tid & 63;
    const int wave = tid >> 6;
    const int wi = wave >> 1, wj = wave & 1;

    const int m0 = blockIdx.y * 128;
    const int n0 = blockIdx.x * 128;
    const int kBase = blockIdx.z * kPerZ;

    // ---- A fragment-direct base: row-tile16 = m0/16 + wi*4 + mi ----
    const __hip_bfloat16* aBase =
        Af + ((size_t)(m0 / 16 + wi * 4) * kcA + (kBase >> 5)) * 512 + lane * 8;
    const size_t aMi = (size_t)kcA * 512;   // mi stride in elems

    // ---- B staging (r5 scheme, 2 chunks of 16 rows per wave) ----
    const int rowInChunk = lane >> 2;
    const int kOff8 = (lane & 3) * 8;
    const __hip_bfloat16* bSrc0 = Brow + (size_t)(n0 + (wave * 2 + 0) * 16 + rowInChunk) * ldb + kBase + kOff8;
    const __hip_bfloat16* bSrc1 = Brow + (size_t)(n0 + (wave * 2 + 1) * 16 + rowInChunk) * ldb + kBase + kOff8;
    // swizzled write offsets (verified conflict-free in r5)
    const int wSlot = (((lane & 3) + ((lane >> 3) & 3)) & 3) * 8;
    const int ldsW0 = (wave * 2 + 0) * 512 + rowInChunk * 32 + wSlot;
    const int ldsW1 = ldsW0 + 512;
    // swizzled read offset parts
    const int rSlot = ((((lane >> 4) + (((lane & 15) >> 1) & 3)) & 3)) * 8;
    const int rRow  = lane & 15;

    floatx4 acc[4][4];
    const floatx4 zero4 = {0.f, 0.f, 0.f, 0.f};
    #pragma unroll
    for (int i = 0; i < 4; i++)
        #pragma unroll
        for (int j = 0; j < 4; j++) acc[i][j] = zero4;

    // A fragment register sets (even / odd k-stages)
    bf16x8 aFe[4], aFo[4];
    // B staging registers (even / odd)
    int4 bRe0, bRe1, bRo0, bRo1;

    // prologue: stage 0 (even) + stage 1 (odd)
    #pragma unroll
    for (int mi = 0; mi < 4; mi++) aFe[mi] = ld8(aBase + mi * aMi);
    bRe0 = *(const int4*)bSrc0; bRe1 = *(const int4*)bSrc1;
    bSrc0 += BK; bSrc1 += BK;
    #pragma unroll
    for (int mi = 0; mi < 4; mi++) aFo[mi] = ld8(aBase + mi * aMi + 512);
    bRo0 = *(const int4*)bSrc0; bRo1 = *(const int4*)bSrc1;
    bSrc0 += BK; bSrc1 += BK;

    *(int4*)(&Bs[0][ldsW0]) = bRe0;
    *(int4*)(&Bs[0][ldsW1]) = bRe1;
    wg_barrier_lds();

    for (int kt = 0; kt < kIters; kt += 2) {
        const bool more = (kt + 2 < kIters);

        // ==== u = 0: compute stage kt (even set, buf 0) ====
        {
            bf16x8 bfr[4];
            #pragma unroll
            for (int nj = 0; nj < 4; nj++)
                bfr[nj] = *(const bf16x8*)(&Bs[0][((wj * 4 + nj) * 16 + rRow) * BK + rSlot]);

            #pragma unroll
            for (int mi = 0; mi < 4; mi++)
                #pragma unroll
                for (int nj = 0; nj < 4; nj++)
                    acc[mi][nj] = __builtin_amdgcn_mfma_f32_16x16x32_bf16(aFe[mi], bfr[nj], acc[mi][nj], 0, 0, 0);

            if (more) {   // prefetch stage kt+2 into even sets
                #pragma unroll
                for (int mi = 0; mi < 4; mi++)
                    aFe[mi] = ld8(aBase + mi * aMi + (size_t)(kt + 2) * 512);
                bRe0 = *(const int4*)bSrc0; bRe1 = *(const int4*)bSrc1;
                bSrc0 += BK; bSrc1 += BK;
            }
            // stage kt+1 (odd regs) -> buf 1; compiler inserts fine vmcnt
            *(int4*)(&Bs[1][ldsW0]) = bRo0;
            *(int4*)(&Bs[1][ldsW1]) = bRo1;

            wg_barrier_lds();   // buf0 reads done everywhere; buf1 visible
        }

        // ==== u = 1: compute stage kt+1 (odd set, buf 1) ====
        {
            bf16x8 bfr[4];
            #pragma unroll
            for (int nj = 0; nj < 4; nj++)
                bfr[nj] = *(const bf16x8*)(&Bs[1][((wj * 4 + nj) * 16 + rRow) * BK + rSlot]);

            #pragma unroll
            for (int mi = 0; mi < 4; mi++)
                #pragma unroll
                for (int nj = 0; nj < 4; nj++)
                    acc[mi][nj] = __builtin_amdgcn_mfma_f32_16x16x32_bf16(aFo[mi], bfr[nj], acc[mi][nj], 0, 0, 0);

            if (more) {   // prefetch stage kt+3 into odd sets
                #pragma unroll
                for (int mi = 0; mi < 4; mi++)
                    aFo[mi] = ld8(aBase + mi * aMi + (size_t)(kt + 3) * 512);
                bRo0 = *(const int4*)bSrc0; bRo1 = *(const int4*)bSrc1;
                bSrc0 += BK; bSrc1 += BK;
                // stage kt+2 (even regs) -> buf 0
                *(int4*)(&Bs[0][ldsW0]) = bRe0;
                *(int4*)(&Bs[0][ldsW1]) = bRe1;
            }

            wg_barrier_lds();
        }
    }

    // epilogue: C/D layout col=lane&15, row=(lane>>4)*4+reg  [verified m89/m91]
    #pragma unroll
    for (int mi = 0; mi < 4; mi++) {
        #pragma unroll
        for (int nj = 0; nj < 4; nj++) {
            #pragma unroll
            for (int r = 0; r < 4; r++) {
                const int orow = m0 + wi * 64 + mi * 16 + (lane >> 4) * 4 + r;
                const int ocol = n0 + wj * 64 + nj * 16 + (lane & 15);
                const float v = acc[mi][nj][r];
                if (MODE == 1) {
                    if (orow < NREAL) {   // orow = graph node n
                        const int b = ocol >> 5, c = ocol & 31;
                        const float t = elu_f(v + bias[c]);
                        // h2f frag: rows b, k=n*32+c, kc=784
                        const size_t ad = ((size_t)(b >> 4) * 784 + orow) * 512
                                        + (c >> 3) * 128 + (b & 15) * 8 + (c & 7);
                        outH[ad] = __float2bfloat16(t);
                    }
                } else {
                    outF[(size_t)blockIdx.z * sliceStride + (size_t)orow * ldc + ocol] = v;
                }
            }
        }
    }
}

// ---------------------------------------------------------------------------
// prepXA: x [1024][784] f32 -> Xf frag (1024 x kc28), zero k-pad
//         a [784][784]  f32 -> Af frag (896 x kc28), zero row/k-pad
// ---------------------------------------------------------------------------
__global__ void prepXA(const float* __restrict__ x, const float* __restrict__ a,
                       __hip_bfloat16* __restrict__ Xf, __hip_bfloat16* __restrict__ Af)
{
    const int XC = (BATCH / 16) * (NPAD / 32);   // 1792 chunks
    int t = blockIdx.x * 256 + threadIdx.x;      // grid exact: (XC+AC)*64
    const float* src;
    __hip_bfloat16* dst;
    int chunk, L, rowsValid;
    if (t < XC * 64) {
        chunk = t >> 6; L = t & 63; src = x; dst = Xf; rowsValid = BATCH;
    } else {
        t -= XC * 64; chunk = t >> 6; L = t & 63; src = a; dst = Af; rowsValid = NREAL;
    }
    const int row = (chunk / 28) * 16 + (L & 15);
    const int k0  = ((chunk % 28) * 4 + (L >> 4)) * 8;
    __hip_bfloat16 o[8];
    if (k0 < NREAL && row < rowsValid) {
        const float4* p = (const float4*)(src + (size_t)row * NREAL + k0);
        const float4 lo = p[0], hi = p[1];
        o[0] = __float2bfloat16(lo.x); o[1] = __float2bfloat16(lo.y);
        o[2] = __float2bfloat16(lo.z); o[3] = __float2bfloat16(lo.w);
        o[4] = __float2bfloat16(hi.x); o[5] = __float2bfloat16(hi.y);
        o[6] = __float2bfloat16(hi.z); o[7] = __float2bfloat16(hi.w);
    } else {
        #pragma unroll
        for (int j = 0; j < 8; j++) o[j] = __float2bfloat16(0.f);
    }
    *(int4*)(dst + (size_t)chunk * 512 + L * 8) = *(const int4*)o;
}

// a [784][784] f32 -> Ar row-major bf16 [896][896], zero-padded (G1 B-operand)
__global__ void convA(const float* __restrict__ a, __hip_bfloat16* __restrict__ Ar) {
    const int idx = blockIdx.x * 256 + threadIdx.x;
    if (idx >= NPAD * NPAD) return;
    const int m = idx % NPAD, n = idx / NPAD;
    const float v = (m < NREAL && n < NREAL) ? a[(size_t)n * NREAL + m] : 0.f;
    Ar[idx] = __float2bfloat16(v);
}

// wf1 [25088][512] fp32 -> Wt row-major bf16 [512][25088] (G4 B-operand)
__global__ void convW(const float* __restrict__ wf1, __hip_bfloat16* __restrict__ Wt) {
    __shared__ float tile[32][33];
    const int k0 = blockIdx.x * 32, h0 = blockIdx.y * 32;
    const int tx = threadIdx.x, ty = threadIdx.y;  // (32,8)
    #pragma unroll
    for (int i = 0; i < 4; i++)
        tile[ty * 4 + i][tx] = wf1[(size_t)(k0 + ty * 4 + i) * HDIM + h0 + tx];
    __syncthreads();
    #pragma unroll
    for (int i = 0; i < 4; i++)
        Wt[(size_t)(h0 + ty * 4 + i) * KFC + k0 + tx] = __float2bfloat16(tile[tx][ty * 4 + i]);
}

// ---------------------------------------------------------------------------
// Layer-1 fused pointwise: reduce KS_G1 Y partials, then
// Tt[(b*32+c)][m] = sum_c' elu(Y[b][m]*w1[c']+b1[c'])*W2[c'][c]  (row-major)
// ---------------------------------------------------------------------------
__global__ void layer1_fuse(const float* __restrict__ Ypart,
                            const float* __restrict__ w1, const float* __restrict__ b1,
                            const float* __restrict__ w2,
                            __hip_bfloat16* __restrict__ Tt)
{
    __shared__ __align__(16) float sW2[C1D * C2D];
    __shared__ float sw1[C1D], sb1[C1D];
    const int tid = threadIdx.x;                 // 128 threads
    for (int i = tid; i < C1D * C2D; i += 128) sW2[i] = w2[i];
    if (tid < C1D) { sw1[tid] = w1[tid]; sb1[tid] = b1[tid]; }
    __syncthreads();

    const int m = blockIdx.x * 128 + tid;        // 0..895
    const int b = blockIdx.y;
    float y = 0.f;
    #pragma unroll
    for (int z = 0; z < KS_G1; z++)
        y += Ypart[(size_t)z * (BATCH * NPAD) + (size_t)b * NPAD + m];

    float h[C1D];
    #pragma unroll
    for (int c1 = 0; c1 < C1D; c1++) h[c1] = elu_f(y * sw1[c1] + sb1[c1]);

    float4 t4[8];
    #pragma unroll
    for (int q = 0; q < 8; q++) t4[q] = make_float4(0.f, 0.f, 0.f, 0.f);
    #pragma unroll
    for (int c1 = 0; c1 < C1D; c1++) {
        const float hv = h[c1];
        const float4* row = (const float4*)(sW2 + c1 * C2D);
        #pragma unroll
        for (int q = 0; q < 8; q++) {
            const float4 w = row[q];
            t4[q].x += hv * w.x; t4[q].y += hv * w.y;
            t4[q].z += hv * w.z; t4[q].w += hv * w.w;
        }
    }
    const float* tf = (const float*)t4;
    #pragma unroll
    for (int c = 0; c < C2D; c++)
        Tt[((size_t)(b * 32 + c)) * NPAD + m] = __float2bfloat16(tf[c]);
}

// ---------------------------------------------------------------------------
// fc1 reduce (split-K partials) + relu + fc2 + softmax, fused.
// ---------------------------------------------------------------------------
__global__ void fc2_softmax(const float* __restrict__ part, const float* __restrict__ bf1,
                            const float* __restrict__ wf2, const float* __restrict__ bf2,
                            float* __restrict__ out)
{
    __shared__ float sW[HDIM * NCLS];
    __shared__ float sb[NCLS];
    const int tid = threadIdx.x;                 // 256
    for (int i = tid; i < HDIM * NCLS; i += 256) sW[i] = wf2[i];
    if (tid < NCLS) sb[tid] = bf2[tid];
    __syncthreads();

    const int lane = tid & 63, wave = tid >> 6;
    const int b = blockIdx.x * 4 + wave;

    float acc[NCLS];
    #pragma unroll
    for (int c = 0; c < NCLS; c++) acc[c] = 0.f;
    #pragma unroll
    for (int q = 0; q < 8; q++) {
        const int h = q * 64 + lane;
        float hv = bf1[h];
        #pragma unroll
        for (int z = 0; z < KS_FC; z++)
            hv += part[(size_t)z * (BATCH * HDIM) + (size_t)b * HDIM + h];
        hv = hv > 0.f ? hv : 0.f;
        #pragma unroll
        for (int c = 0; c < NCLS; c++) acc[c] += hv * sW[h * NCLS + c];
    }
    #pragma unroll
    for (int c = 0; c < NCLS; c++) {
        #pragma unroll
        for (int off = 32; off >= 1; off >>= 1) acc[c] += __shfl_down(acc[c], off);
    }
    if (lane == 0) {
        float mx = -1e30f;
        #pragma unroll
        for (int c = 0; c < NCLS; c++) { acc[c] += sb[c]; mx = fmaxf(mx, acc[c]); }
        float e[NCLS], s = 0.f;
        #pragma unroll
        for (int c = 0; c < NCLS; c++) { e[c] = __expf(acc[c] - mx); s += e[c]; }
        const float inv = 1.f / s;
        #pragma unroll
        for (int c = 0; c < NCLS; c++) out[(size_t)b * NCLS + c] = e[c] * inv;
    }
}

// ---------------------------------------------------------------------------
// Workspace layout (peak ~115.1 MB; ws >= 119.3 MB proven in r1)
//   h2f   [0,          51380224)  bf16 FRAG 1024 x kc784 (written G3, read G4)
//     Ypart [0, 25690112) f32 7x1024x896 — overlay, dead before G3
//   Tt    [51380224,  110100480)  bf16 row-major 32768x896 (dead after G3)
//     Wt   [51380224, 77070336)   bf16 row-major 512x25088 — overlay post-G3
//     part [77070336, 106430464)  f32 14x1024x512 — overlay post-G3
//   Af    [110100480, 111706112)  bf16 FRAG 896 x kc28
//   Xf    [111706112, 113541120)  bf16 FRAG 1024 x kc28
//   Ar    [113541120, 115146752)  bf16 row-major 896x896
// ---------------------------------------------------------------------------
extern "C" void kernel_launch(void* const* d_in, const int* in_sizes, int n_in,
                              void* d_out, int out_size, void* d_ws, size_t ws_size,
                              hipStream_t stream)
{
    const float* x   = (const float*)d_in[0];
    const float* a   = (const float*)d_in[1];
    const float* w1  = (const float*)d_in[2];
    const float* b1  = (const float*)d_in[3];
    const float* w2  = (const float*)d_in[4];
    const float* b2  = (const float*)d_in[5];
    const float* wf1 = (const float*)d_in[6];
    const float* bf1 = (const float*)d_in[7];
    const float* wf2 = (const float*)d_in[8];
    const float* bf2 = (const float*)d_in[9];
    float* out = (float*)d_out;

    char* ws = (char*)d_ws;
    __hip_bfloat16* h2f  = (__hip_bfloat16*)(ws + 0);
    float*          Ypart= (float*)(ws + 0);                  // overlay (pre-G3)
    __hip_bfloat16* Tt   = (__hip_bfloat16*)(ws + 51380224);
    __hip_bfloat16* Wt   = (__hip_bfloat16*)(ws + 51380224);  // overlay (post-G3)
    float*          part = (float*)(ws + 77070336);           // overlay (post-G3)
    __hip_bfloat16* Af   = (__hip_bfloat16*)(ws + 110100480);
    __hip_bfloat16* Xf   = (__hip_bfloat16*)(ws + 111706112);
    __hip_bfloat16* Ar   = (__hip_bfloat16*)(ws + 113541120);

    // 1) frag-convert x, a; row-major a
    prepXA<<<840, 256, 0, stream>>>(x, a, Xf, Af);
    convA<<<(NPAD * NPAD + 255) / 256, 256, 0, stream>>>(a, Ar);

    // 2) G1: Ypart[z][b][n] partials (A=Xf frag rows b, B=Ar rows n)
    //    grid 7x8x7 = 392 blocks, 4 iters
    gemm_hy<2><<<dim3(NPAD / 128, BATCH / 128, KS_G1), 256, 0, stream>>>(
        Xf, 28, Ar, NPAD, (NPAD / KS_G1) / BK, NPAD / KS_G1,
        (size_t)BATCH * NPAD, Ypart, NPAD, nullptr, nullptr);

    // 3) layer-1 pointwise + @W2 -> Tt row-major
    layer1_fuse<<<dim3(NPAD / 128, BATCH), 128, 0, stream>>>(Ypart, w1, b1, w2, Tt);

    // 4) G3: h2 = elu(A @ T + b2) -> h2f frag  (A=Af frag rows n, B=Tt rows (b,c))
    //    grid 256x7 = 1792 blocks, 28 iters
    gemm_hy<1><<<dim3((BATCH * 32) / 128, NPAD / 128, 1), 256, 0, stream>>>(
        Af, 28, Tt, NPAD, NPAD / BK, 0, 0, nullptr, 0, h2f, b2);

    // 5) wf1 -> Wt row-major (into dead-Tt region)
    convW<<<dim3(KFC / 32, HDIM / 32), dim3(32, 8), 0, stream>>>(wf1, Wt);

    // 6) G4: fc1 partials (A=h2f frag rows b, B=Wt rows H), grid 4x8x14, 56 iters
    gemm_hy<2><<<dim3(HDIM / 128, BATCH / 128, KS_FC), 256, 0, stream>>>(
        h2f, 784, Wt, KFC, (KFC / KS_FC) / BK, KFC / KS_FC,
        (size_t)BATCH * HDIM, part, HDIM, nullptr, nullptr);

    // 7) fc1 reduce + relu + fc2 + softmax
    fc2_softmax<<<BATCH / 4, 256, 0, stream>>>(part, bf1, wf2, bf2, out);
}